// Round 18
// baseline (97.305 us; speedup 1.0000x reference)
//
#include <hip/hip_runtime.h>
#include <hip/hip_bf16.h>
#include <cstdint>
#include <cstddef>

typedef __attribute__((ext_vector_type(8))) __bf16 bf16x8;
typedef __attribute__((ext_vector_type(4))) float f32x4;
typedef __attribute__((ext_vector_type(16))) float f32x16;

__device__ __forceinline__ ushort f2b(float x) {
    union { float f; uint32_t u; } v; v.f = x;
    uint32_t r = v.u + 0x7FFFu + ((v.u >> 16) & 1u);   // RNE
    return (ushort)(r >> 16);
}

__device__ __forceinline__ float b2f(ushort u) {
    union { uint32_t u; float f; } v; v.u = (uint32_t)u << 16;
    return v.f;
}

__device__ __forceinline__ void glds16(const void* g, void* l) {
    __builtin_amdgcn_global_load_lds(
        (const __attribute__((address_space(1))) void*)g,
        (__attribute__((address_space(3))) void*)l, 16, 0, 0);
}

__device__ __forceinline__ uint32_t cvt_pk_bf16(float lo, float hi) {
    uint32_t r;
    asm("v_cvt_pk_bf16_f32 %0, %1, %2" : "=v"(r) : "v"(lo), "v"(hi));
    return r;
}

// v_permlane32_swap_b32 a, b:  a.hi32lanes <-> b.lo32lanes
__device__ __forceinline__ void plane_swap(uint32_t& a, uint32_t& b) {
    asm volatile("v_permlane32_swap_b32 %0, %1" : "+v"(a), "+v"(b));
}

__device__ __forceinline__ f32x16 z16() {
    f32x16 v;
#pragma unroll
    for (int i = 0; i < 16; ++i) v[i] = 0.f;
    return v;
}

// ---------------- fused prep: x->bf16 convert + both weight transposes ----------------
__global__ __launch_bounds__(256) void k_prep(const float* __restrict__ x,
                                              ushort* __restrict__ xb,
                                              const float* __restrict__ Wqkv,
                                              ushort* __restrict__ wqkvT,
                                              const float* __restrict__ Wout,
                                              ushort* __restrict__ woutT) {
    __shared__ float tile[32][33];
    const int id = blockIdx.x;
    const int tid = threadIdx.x;
    if (id < 2048) {
        const int i = id * 256 + tid;
        const float4* p = (const float4*)x + (size_t)i * 2;
        float4 a = p[0], b = p[1];
        ushort o[8] = { f2b(a.x), f2b(a.y), f2b(a.z), f2b(a.w),
                        f2b(b.x), f2b(b.y), f2b(b.z), f2b(b.w) };
        *(uint4*)(xb + (size_t)i * 8) = *(const uint4*)o;
        return;
    }
    const float* in;
    ushort* out;
    int R = 512, C, c0, r0;
    if (id < 2816) {
        in = Wqkv; out = wqkvT; C = 1536;
        c0 = ((id - 2048) % 48) * 32; r0 = ((id - 2048) / 48) * 32;
    } else {
        in = Wout; out = woutT; C = 512;
        c0 = ((id - 2816) % 16) * 32; r0 = ((id - 2816) / 16) * 32;
    }
    const int tx = tid & 31, ty = tid >> 5;       // (32,8)
#pragma unroll
    for (int i = 0; i < 32; i += 8)
        tile[ty + i][tx] = in[(size_t)(r0 + ty + i) * C + c0 + tx];
    __syncthreads();
#pragma unroll
    for (int i = 0; i < 32; i += 8)
        out[(size_t)(c0 + ty + i) * R + r0 + tx] = f2b(tile[tx][ty + i]);
}

// ---------------- bf16 GEMM, A [M][K] x BT [N][K] (=B^T), (32*MP)x128 tile -------------
template <int MODE, int MP>
__global__ __launch_bounds__(256) void k_gemm(const ushort* __restrict__ A,
                                              const ushort* __restrict__ BT,
                                              const float* __restrict__ bias,
                                              float* __restrict__ outF,
                                              ushort* __restrict__ Qp,
                                              ushort* __restrict__ Kp,
                                              ushort* __restrict__ VTp,
                                              int K) {
    __shared__ __align__(16) ushort lA[2][MP * 1024];
    __shared__ __align__(16) ushort lB[2][4096];
    const int tid = threadIdx.x;
    const int lane = tid & 63, lr = lane & 15, lg = lane >> 4;
    const int wid = tid >> 6, wm = wid >> 1, wn = wid & 1;
    const int m0 = blockIdx.x * (32 * MP), n0 = blockIdx.y * 128;

    const ushort* ga = A + (size_t)(m0 + (tid >> 2)) * K + (tid & 3) * 8;
    const ushort* gb = BT + (size_t)(n0 + (tid >> 2)) * K + (tid & 3) * 8;
    const size_t rstep = (size_t)64 * K;

    float bvv[4];
#pragma unroll
    for (int n = 0; n < 4; ++n) bvv[n] = bias[n0 + wn * 64 + n * 16 + lr];
    asm volatile("s_waitcnt vmcnt(0)" ::: "memory");
    __builtin_amdgcn_sched_barrier(0);

    f32x4 zero = {0.f, 0.f, 0.f, 0.f};
    f32x4 acc[MP][4];
#pragma unroll
    for (int i = 0; i < MP; ++i)
#pragma unroll
        for (int j = 0; j < 4; ++j) acc[i][j] = zero;

    auto STG = [&](int buf, int k0) {
        glds16(ga + k0, &lA[buf][tid * 8]);
        if constexpr (MP == 4) glds16(ga + k0 + rstep, &lA[buf][2048 + tid * 8]);
        glds16(gb + k0,         &lB[buf][tid * 8]);
        glds16(gb + k0 + rstep, &lB[buf][2048 + tid * 8]);
    };

    const int NT = K >> 5;
    STG(0, 0);
    for (int it = 0; it < NT; ++it) {
        const int bsel = it & 1;
        if (it + 1 < NT) {
            STG(bsel ^ 1, (it + 1) * 32);
            if constexpr (MP == 4) {
                asm volatile("s_waitcnt vmcnt(4)" ::: "memory");
            } else {
                asm volatile("s_waitcnt vmcnt(3)" ::: "memory");
            }
        } else {
            asm volatile("s_waitcnt vmcnt(0)" ::: "memory");
        }
        __builtin_amdgcn_sched_barrier(0);
        __builtin_amdgcn_s_barrier();
        asm volatile("" ::: "memory");

        bf16x8 af[MP], bfr[4];
#pragma unroll
        for (int m = 0; m < MP; ++m)
            af[m] = *(const bf16x8*)&lA[bsel][(wm * (16 * MP) + m * 16 + lr) * 32 + lg * 8];
#pragma unroll
        for (int n = 0; n < 4; ++n)
            bfr[n] = *(const bf16x8*)&lB[bsel][(wn * 64 + n * 16 + lr) * 32 + lg * 8];
#pragma unroll
        for (int m = 0; m < MP; ++m)
#pragma unroll
            for (int n = 0; n < 4; ++n)
                acc[m][n] = __builtin_amdgcn_mfma_f32_16x16x32_bf16(af[m], bfr[n], acc[m][n], 0, 0, 0);

        asm volatile("" ::: "memory");
        __builtin_amdgcn_s_barrier();
    }

#pragma unroll
    for (int n = 0; n < 4; ++n) {
        const int gn = n0 + wn * 64 + n * 16 + lr;
        const float bv = bvv[n];
#pragma unroll
        for (int m = 0; m < MP; ++m) {
            const int gmb = m0 + wm * (16 * MP) + m * 16 + lg * 4;
            if (MODE == 0) {
                const int sec = gn >> 9, c = gn & 511;
                const int h = c >> 6, d = c & 63;
                const int b = gmb >> 12, t = gmb & 4095;
                if (sec == 2) {
                    ushort tmp[4];
#pragma unroll
                    for (int r = 0; r < 4; ++r) tmp[r] = f2b(acc[m][n][r] + bv);
                    *(ushort4*)&VTp[(size_t)(b * 8 + h) * 262144 + (size_t)d * 4096 + t] =
                        *(const ushort4*)tmp;
                } else {
                    const size_t idx0 = ((size_t)(b * 8 + h) * 4096 + t) * 64 + d;
#pragma unroll
                    for (int r = 0; r < 4; ++r) {
                        const float v = acc[m][n][r] + bv;
                        // Q scale = 0.125 * log2(e), folded in f32 -> exp2 domain
                        if (sec == 0) Qp[idx0 + (size_t)r * 64] = f2b(v * 0.18033688f);
                        else          Kp[idx0 + (size_t)r * 64] = f2b(v);
                    }
                }
            } else {
#pragma unroll
                for (int r = 0; r < 4; ++r)
                    outF[(size_t)(gmb + r) * 512 + gn] = acc[m][n][r] + bv;
            }
        }
    }
}

// ---------------- attention stream: 8 waves, one 256-row q-tile, KV [kv_lo,kv_hi) -------
// KV tile = 64 rows; 256-row q-tile qt (0..15) covers kv units [0, 4*qt+4).
// All 8 waves consume ONE shared KV stream in lockstep; staging = 2 glds16/thread.
// NO max-tracking (log2e pre-folded into Q; exp2 direct); pure-sum partials.
// ALWAYS writes a bf16 partial O [256 q][64 d] (q-major) + l f32 [256] to its slot.
__device__ __forceinline__ void attn_run(const ushort* __restrict__ Qb,
                                         const ushort* __restrict__ Kb,
                                         const ushort* __restrict__ Vb,
                                         ushort* sm, int qt, int kv_lo, int kv_hi,
                                         int lane, int w, int tid,
                                         ushort* __restrict__ pOb,
                                         float* __restrict__ pL) {
    const int lg2 = lane >> 5, l31 = lane & 31, l7 = lane & 7;
    const int q0 = qt * 256;
    const int qbase = q0 + w * 32;

    // Q fragments: B-operand of 32x32x16 (col = lane&31 -> q row, k = (lane>>5)*8+e)
    bf16x8 qf[4];
#pragma unroll
    for (int ks = 0; ks < 4; ++ks)
        qf[ks] = *(const bf16x8*)&Qb[(size_t)(qbase + l31) * 64 + ks * 16 + lg2 * 8];
    asm volatile("s_waitcnt vmcnt(0)" ::: "memory");   // exact in-loop vmcnt counting
    __builtin_amdgcn_sched_barrier(0);

    const int srow = tid >> 3;                    // 0..63 (row within unit)
    const int sslot = (tid & 7) ^ (srow & 7);     // pre-swizzled global slot (rule 21)

    auto STAGE = [&](int buf, int kv0) {          // 2 glds16 per thread (512 thr = 16KB)
        glds16(Kb + (size_t)(kv0 + srow) * 64 + sslot * 8,
               (char*)sm + buf * 16384 + w * 1024);
        glds16(Vb + (size_t)srow * 4096 + kv0 + sslot * 8,
               (char*)sm + buf * 16384 + 8192 + w * 1024);
    };

    f32x16 oacc0 = z16(), oacc1 = z16();          // O^T: col=q (lane&31), rows=d pattern
    float lrun = 0.f;

    STAGE(0, kv_lo * 64);
    for (int it = kv_lo; it < kv_hi; ++it) {
        const int kv0 = it * 64;
        const int bsel = (it - kv_lo) & 1;
        if (it + 1 < kv_hi) {
            STAGE(bsel ^ 1, kv0 + 64);
            asm volatile("s_waitcnt vmcnt(2)" ::: "memory");
        } else {
            asm volatile("s_waitcnt vmcnt(0)" ::: "memory");
        }
        __builtin_amdgcn_sched_barrier(0);
        __builtin_amdgcn_s_barrier();             // all waves: buf[bsel] resident
        asm volatile("" ::: "memory");

        const bool live0 = (kv0 <= qbase + 31);
        const bool live1 = (kv0 + 32 <= qbase + 31);
        if (live0) {
            const ushort* bK = sm + bsel * 8192;
            const ushort* bV = bK + 4096;

            // S^T = K x Q^T : col = q = lane&31, kv rows reg-distributed
            f32x16 st0 = z16(), st1 = z16();
            __builtin_amdgcn_s_setprio(1);
#pragma unroll
            for (int ks = 0; ks < 4; ++ks) {
                bf16x8 kf = *(const bf16x8*)&bK[l31 * 64 + (((2 * ks + lg2) ^ l7)) * 8];
                st0 = __builtin_amdgcn_mfma_f32_32x32x16_bf16(kf, qf[ks], st0, 0, 0, 0);
            }
            if (live1) {
#pragma unroll
                for (int ks = 0; ks < 4; ++ks) {
                    bf16x8 kf = *(const bf16x8*)&bK[(32 + l31) * 64 + (((2 * ks + lg2) ^ l7)) * 8];
                    st1 = __builtin_amdgcn_mfma_f32_32x32x16_bf16(kf, qf[ks], st1, 0, 0, 0);
                }
            }
            __builtin_amdgcn_s_setprio(0);
            if (kv0 == qbase) {                   // diagonal tile 0
#pragma unroll
                for (int r = 0; r < 16; ++r) {
                    const int rowk = (r & 3) + 8 * (r >> 2) + 4 * lg2;
                    if (rowk > l31) st0[r] = -1e30f;
                }
            }
            if (live1 && kv0 + 32 == qbase) {     // diagonal tile 1
#pragma unroll
                for (int r = 0; r < 16; ++r) {
                    const int rowk = (r & 3) + 8 * (r >> 2) + 4 * lg2;
                    if (rowk > l31) st1[r] = -1e30f;
                }
            }

            // p = exp2(s) (log2e folded into Q); l accumulates per-lane
            float s0 = 0.f, s1 = 0.f, s2 = 0.f, s3 = 0.f;
#pragma unroll
            for (int r = 0; r < 16; r += 4) {
                st0[r]     = __builtin_amdgcn_exp2f(st0[r]);     s0 += st0[r];
                st0[r + 1] = __builtin_amdgcn_exp2f(st0[r + 1]); s1 += st0[r + 1];
                st0[r + 2] = __builtin_amdgcn_exp2f(st0[r + 2]); s2 += st0[r + 2];
                st0[r + 3] = __builtin_amdgcn_exp2f(st0[r + 3]); s3 += st0[r + 3];
            }
            if (live1) {
#pragma unroll
                for (int r = 0; r < 16; r += 4) {
                    st1[r]     = __builtin_amdgcn_exp2f(st1[r]);     s0 += st1[r];
                    st1[r + 1] = __builtin_amdgcn_exp2f(st1[r + 1]); s1 += st1[r + 1];
                    st1[r + 2] = __builtin_amdgcn_exp2f(st1[r + 2]); s2 += st1[r + 2];
                    st1[r + 3] = __builtin_amdgcn_exp2f(st1[r + 3]); s3 += st1[r + 3];
                }
            }
            lrun += (s0 + s1) + (s2 + s3);

            // P -> bf16 B-frag via cvt_pk + permlane32_swap (T12), then PV
#pragma unroll
            for (int stp = 0; stp < 4; ++stp) {
                if (stp >= 2 && !live1) continue;
                const int h = stp & 1;
                uint32_t a0, a1, b0, b1;
                if (stp < 2) {
                    a0 = cvt_pk_bf16(st0[h * 8 + 0], st0[h * 8 + 1]);
                    a1 = cvt_pk_bf16(st0[h * 8 + 2], st0[h * 8 + 3]);
                    b0 = cvt_pk_bf16(st0[h * 8 + 4], st0[h * 8 + 5]);
                    b1 = cvt_pk_bf16(st0[h * 8 + 6], st0[h * 8 + 7]);
                } else {
                    a0 = cvt_pk_bf16(st1[h * 8 + 0], st1[h * 8 + 1]);
                    a1 = cvt_pk_bf16(st1[h * 8 + 2], st1[h * 8 + 3]);
                    b0 = cvt_pk_bf16(st1[h * 8 + 4], st1[h * 8 + 5]);
                    b1 = cvt_pk_bf16(st1[h * 8 + 6], st1[h * 8 + 7]);
                }
                plane_swap(a0, b0);
                plane_swap(a1, b1);
                union { uint32_t u[4]; bf16x8 v; } pk;
                pk.u[0] = a0; pk.u[1] = a1; pk.u[2] = b0; pk.u[3] = b1;
                const int vs = (((2 * stp + lg2) ^ l7)) * 8;
                bf16x8 vf0 = *(const bf16x8*)&bV[l31 * 64 + vs];
                bf16x8 vf1 = *(const bf16x8*)&bV[(32 + l31) * 64 + vs];
                __builtin_amdgcn_s_setprio(1);
                oacc0 = __builtin_amdgcn_mfma_f32_32x32x16_bf16(vf0, pk.v, oacc0, 0, 0, 0);
                oacc1 = __builtin_amdgcn_mfma_f32_32x32x16_bf16(vf1, pk.v, oacc1, 0, 0, 0);
                __builtin_amdgcn_s_setprio(0);
            }
        }
        asm volatile("" ::: "memory");
        __builtin_amdgcn_s_barrier();             // all reads of buf[bsel] done
    }

    // deferred cross-half l reduction, then q-major bf16 partial write (ushort4 packs:
    // for r = r0*4+j, dd = j + 8*r0 + 4*lg2 -> 4 consecutive dd per r0)
    lrun += __shfl_xor(lrun, 32);
    const int qc = w * 32 + l31;
#pragma unroll
    for (int r0 = 0; r0 < 4; ++r0) {
        ushort t0[4], t1[4];
#pragma unroll
        for (int j = 0; j < 4; ++j) {
            t0[j] = f2b(oacc0[r0 * 4 + j]);
            t1[j] = f2b(oacc1[r0 * 4 + j]);
        }
        const int db = 8 * r0 + 4 * lg2;
        *(ushort4*)&pOb[qc * 64 + db]      = *(const ushort4*)t0;
        *(ushort4*)&pOb[qc * 64 + 32 + db] = *(const ushort4*)t1;
    }
    if (lg2 == 0) pL[qc] = lrun;
}

// 4-way fold+split causal attention over 256-row q-tiles.
// Pair (p, 15-p), p in [0,8): heavy nH = 64-4p units, light nL = 4p+4, total 68.
// 4 streams of 17 units each: s -> p=s>>2, half=(s>>1)&1, sub=s&1.
// 512 blocks x 8 waves = 2 blocks/CU, all blocks exactly 17 units.
__global__ __launch_bounds__(512) void k_attn(const ushort* __restrict__ Q,
                                              const ushort* __restrict__ K,
                                              const ushort* __restrict__ VT,
                                              ushort* __restrict__ hOb,
                                              ushort* __restrict__ lOb,
                                              float* __restrict__ pL) {
    __shared__ __align__(16) ushort sm[16384];    // 32KB: 2 staging bufs x 16KB
    const int tid = threadIdx.x;
    const int lane = tid & 63, w = tid >> 6;      // w in [0,8)
    const int bh = blockIdx.x;
    const int s = blockIdx.y;                     // 0..31
    const int p = s >> 2, half = (s >> 1) & 1, sub = s & 1;
    const size_t base = (size_t)bh * 4096 * 64;
    const ushort* Qb = Q + base;
    const ushort* Kb = K + base;
    const ushort* Vb = VT + base;                 // [64][4096]

    const int pairbase = bh * 8 + p;
    if (half == 0) {
        const size_t hs = (size_t)(pairbase * 4 + sub);
        attn_run(Qb, Kb, Vb, sm, 15 - p, 17 * sub, 17 * sub + 17, lane, w, tid,
                 hOb + hs * 16384, pL + hs * 256);
    } else {
        const int nH2 = 30 - 4 * p;
        if (17 * sub < nH2) {
            const int hi = 17 * sub + 17 < nH2 ? 17 * sub + 17 : nH2;
            const size_t hs = (size_t)(pairbase * 4 + 2 + sub);
            attn_run(Qb, Kb, Vb, sm, 15 - p, 34 + 17 * sub, 34 + hi, lane, w, tid,
                     hOb + hs * 16384, pL + hs * 256);
        }
        if (17 * sub + 17 > nH2) {
            const int nL = 4 * p + 4;
            int llo = 17 * sub - nH2; if (llo < 0) llo = 0;
            int lhi = 17 * sub + 17 - nH2; if (lhi > nL) lhi = nL;
            const int lidx = (p <= 3) ? 0 : sub;
            const size_t ls = (size_t)(pairbase * 2 + lidx);
            attn_run(Qb, Kb, Vb, sm, p, llo, lhi, lane, w, tid,
                     lOb + ls * 16384, pL + (size_t)(512 + ls) * 256);
        }
    }
}

// merge the k q-major bf16 partials of each (bh, qt), divide by summed l, write bf16 xb
__global__ __launch_bounds__(512) void k_merge(const ushort* __restrict__ hOb,
                                               const ushort* __restrict__ lOb,
                                               const float* __restrict__ pL,
                                               ushort* __restrict__ Outp) {
    const int bh = blockIdx.x;                    // 16
    const int qt = blockIdx.y;                    // 16
    const int tid = threadIdx.x;                  // 512
    const int q = tid >> 1, dh = (tid & 1) * 32;

    int k;
    const ushort* Ob;
    const float* Lb;
    if (qt >= 8) {                                // heavy tile: p = 15-qt
        const int p = 15 - qt;
        k = (p <= 3) ? 4 : 3;
        const size_t s0 = (size_t)((bh * 8 + p) * 4);
        Ob = hOb + s0 * 16384;
        Lb = pL + s0 * 256;
    } else {                                      // light tile: p = qt
        const int p = qt;
        k = (p <= 3) ? 1 : 2;
        const size_t s0 = (size_t)((bh * 8 + p) * 2);
        Ob = lOb + s0 * 16384;
        Lb = pL + (size_t)(512 + s0) * 256;
    }

    float osum[32];
#pragma unroll
    for (int e = 0; e < 32; ++e) osum[e] = 0.f;
    float lsum = 0.f;
    for (int j = 0; j < k; ++j) {
        const ushort* O = Ob + (size_t)j * 16384 + q * 64 + dh;   // q-major, contiguous dd
#pragma unroll
        for (int v = 0; v < 4; ++v) {
            uint4 pkv = *(const uint4*)&O[v * 8];
            const ushort* us = (const ushort*)&pkv;
#pragma unroll
            for (int e2 = 0; e2 < 8; ++e2) osum[v * 8 + e2] += b2f(us[e2]);
        }
        lsum += Lb[(size_t)j * 256 + q];
    }
    const float inv = 1.0f / lsum;
    ushort outv[32];
#pragma unroll
    for (int e = 0; e < 32; ++e) outv[e] = f2b(osum[e] * inv);
    const int b = bh >> 3, h = bh & 7;
    const int t = qt * 256 + q;
    ushort* op = Outp + ((size_t)(b * 4096 + t) * 512 + h * 64 + dh);
#pragma unroll
    for (int j = 0; j < 4; ++j) *(uint4*)&op[j * 8] = *(const uint4*)&outv[j * 8];
}

extern "C" void kernel_launch(void* const* d_in, const int* in_sizes, int n_in,
                              void* d_out, int out_size, void* d_ws, size_t ws_size,
                              hipStream_t stream) {
    const float* x    = (const float*)d_in[0];
    const float* Wqkv = (const float*)d_in[1];
    const float* bqkv = (const float*)d_in[2];
    const float* Wout = (const float*)d_in[3];
    const float* bout = (const float*)d_in[4];
    float* out = (float*)d_out;

    char* ws = (char*)d_ws;
    ushort* xb    = (ushort*)(ws);                 // 8 MB (attn out)
    ushort* wqkvT = (ushort*)(ws + 8388608);       // 1.5 MB (dead after gemm<0>; pL reuses)
    ushort* woutT = (ushort*)(ws + 9961472);       // 0.5 MB
    ushort* Qp    = (ushort*)(ws + 10485760);      // 8 MB
    ushort* Kp    = (ushort*)(ws + 18874368);      // 8 MB
    ushort* VTp   = (ushort*)(ws + 27262976);      // 8 MB
    ushort* hOb   = (ushort*)(ws + 35651584);      // 16 MB: 512 heavy bf16 slots x 32KB
    ushort* lOb   = (ushort*)d_out;                // 8 MB: 256 light bf16 slots (scratch;
                                                   // gemm<1> overwrites d_out afterwards)
    float*  pL    = (float*)(ws + 8388608);        // 768 KB in dead wqkvT region

    k_prep<<<3072, 256, 0, stream>>>(x, xb, Wqkv, wqkvT, Wout, woutT);
    k_gemm<0, 4><<<dim3(64, 12), 256, 0, stream>>>(xb, wqkvT, bqkv, nullptr, Qp, Kp, VTp, 512);
    k_attn<<<dim3(16, 32), 512, 0, stream>>>(Qp, Kp, VTp, hOb, lOb, pL);
    k_merge<<<dim3(16, 16), 512, 0, stream>>>(hOb, lOb, pL, xb);
    k_gemm<1, 2><<<dim3(128, 4), 256, 0, stream>>>(xb, woutT, bout, out, nullptr, nullptr, nullptr, 512);
}

// Round 19
// 97.143 us; speedup vs baseline: 1.0017x; 1.0017x over previous
//
#include <hip/hip_runtime.h>
#include <hip/hip_bf16.h>
#include <cstdint>
#include <cstddef>

typedef __attribute__((ext_vector_type(8))) __bf16 bf16x8;
typedef __attribute__((ext_vector_type(4))) float f32x4;
typedef __attribute__((ext_vector_type(16))) float f32x16;

__device__ __forceinline__ ushort f2b(float x) {
    union { float f; uint32_t u; } v; v.f = x;
    uint32_t r = v.u + 0x7FFFu + ((v.u >> 16) & 1u);   // RNE
    return (ushort)(r >> 16);
}

__device__ __forceinline__ float b2f(ushort u) {
    union { uint32_t u; float f; } v; v.u = (uint32_t)u << 16;
    return v.f;
}

__device__ __forceinline__ void glds16(const void* g, void* l) {
    __builtin_amdgcn_global_load_lds(
        (const __attribute__((address_space(1))) void*)g,
        (__attribute__((address_space(3))) void*)l, 16, 0, 0);
}

__device__ __forceinline__ uint32_t cvt_pk_bf16(float lo, float hi) {
    uint32_t r;
    asm("v_cvt_pk_bf16_f32 %0, %1, %2" : "=v"(r) : "v"(lo), "v"(hi));
    return r;
}

// v_permlane32_swap_b32 a, b:  a.hi32lanes <-> b.lo32lanes
__device__ __forceinline__ void plane_swap(uint32_t& a, uint32_t& b) {
    asm volatile("v_permlane32_swap_b32 %0, %1" : "+v"(a), "+v"(b));
}

__device__ __forceinline__ f32x16 z16() {
    f32x16 v;
#pragma unroll
    for (int i = 0; i < 16; ++i) v[i] = 0.f;
    return v;
}

// ---------------- fused prep: x->bf16 convert + both weight transposes ----------------
__global__ __launch_bounds__(256) void k_prep(const float* __restrict__ x,
                                              ushort* __restrict__ xb,
                                              const float* __restrict__ Wqkv,
                                              ushort* __restrict__ wqkvT,
                                              const float* __restrict__ Wout,
                                              ushort* __restrict__ woutT) {
    __shared__ float tile[32][33];
    const int id = blockIdx.x;
    const int tid = threadIdx.x;
    if (id < 2048) {
        const int i = id * 256 + tid;
        const float4* p = (const float4*)x + (size_t)i * 2;
        float4 a = p[0], b = p[1];
        ushort o[8] = { f2b(a.x), f2b(a.y), f2b(a.z), f2b(a.w),
                        f2b(b.x), f2b(b.y), f2b(b.z), f2b(b.w) };
        *(uint4*)(xb + (size_t)i * 8) = *(const uint4*)o;
        return;
    }
    const float* in;
    ushort* out;
    int R = 512, C, c0, r0;
    if (id < 2816) {
        in = Wqkv; out = wqkvT; C = 1536;
        c0 = ((id - 2048) % 48) * 32; r0 = ((id - 2048) / 48) * 32;
    } else {
        in = Wout; out = woutT; C = 512;
        c0 = ((id - 2816) % 16) * 32; r0 = ((id - 2816) / 16) * 32;
    }
    const int tx = tid & 31, ty = tid >> 5;       // (32,8)
#pragma unroll
    for (int i = 0; i < 32; i += 8)
        tile[ty + i][tx] = in[(size_t)(r0 + ty + i) * C + c0 + tx];
    __syncthreads();
#pragma unroll
    for (int i = 0; i < 32; i += 8)
        out[(size_t)(c0 + ty + i) * R + r0 + tx] = f2b(tile[tx][ty + i]);
}

// ---------------- bf16 GEMM, A [M][K] x BT [N][K] (=B^T), (32*MP)x128 tile -------------
template <int MODE, int MP>
__global__ __launch_bounds__(256) void k_gemm(const ushort* __restrict__ A,
                                              const ushort* __restrict__ BT,
                                              const float* __restrict__ bias,
                                              float* __restrict__ outF,
                                              ushort* __restrict__ Qp,
                                              ushort* __restrict__ Kp,
                                              ushort* __restrict__ VTp,
                                              int K) {
    __shared__ __align__(16) ushort lA[2][MP * 1024];
    __shared__ __align__(16) ushort lB[2][4096];
    const int tid = threadIdx.x;
    const int lane = tid & 63, lr = lane & 15, lg = lane >> 4;
    const int wid = tid >> 6, wm = wid >> 1, wn = wid & 1;
    const int m0 = blockIdx.x * (32 * MP), n0 = blockIdx.y * 128;

    const ushort* ga = A + (size_t)(m0 + (tid >> 2)) * K + (tid & 3) * 8;
    const ushort* gb = BT + (size_t)(n0 + (tid >> 2)) * K + (tid & 3) * 8;
    const size_t rstep = (size_t)64 * K;

    float bvv[4];
#pragma unroll
    for (int n = 0; n < 4; ++n) bvv[n] = bias[n0 + wn * 64 + n * 16 + lr];
    asm volatile("s_waitcnt vmcnt(0)" ::: "memory");
    __builtin_amdgcn_sched_barrier(0);

    f32x4 zero = {0.f, 0.f, 0.f, 0.f};
    f32x4 acc[MP][4];
#pragma unroll
    for (int i = 0; i < MP; ++i)
#pragma unroll
        for (int j = 0; j < 4; ++j) acc[i][j] = zero;

    auto STG = [&](int buf, int k0) {
        glds16(ga + k0, &lA[buf][tid * 8]);
        if constexpr (MP == 4) glds16(ga + k0 + rstep, &lA[buf][2048 + tid * 8]);
        glds16(gb + k0,         &lB[buf][tid * 8]);
        glds16(gb + k0 + rstep, &lB[buf][2048 + tid * 8]);
    };

    const int NT = K >> 5;
    STG(0, 0);
    for (int it = 0; it < NT; ++it) {
        const int bsel = it & 1;
        if (it + 1 < NT) {
            STG(bsel ^ 1, (it + 1) * 32);
            if constexpr (MP == 4) {
                asm volatile("s_waitcnt vmcnt(4)" ::: "memory");
            } else {
                asm volatile("s_waitcnt vmcnt(3)" ::: "memory");
            }
        } else {
            asm volatile("s_waitcnt vmcnt(0)" ::: "memory");
        }
        __builtin_amdgcn_sched_barrier(0);
        __builtin_amdgcn_s_barrier();
        asm volatile("" ::: "memory");

        bf16x8 af[MP], bfr[4];
#pragma unroll
        for (int m = 0; m < MP; ++m)
            af[m] = *(const bf16x8*)&lA[bsel][(wm * (16 * MP) + m * 16 + lr) * 32 + lg * 8];
#pragma unroll
        for (int n = 0; n < 4; ++n)
            bfr[n] = *(const bf16x8*)&lB[bsel][(wn * 64 + n * 16 + lr) * 32 + lg * 8];
#pragma unroll
        for (int m = 0; m < MP; ++m)
#pragma unroll
            for (int n = 0; n < 4; ++n)
                acc[m][n] = __builtin_amdgcn_mfma_f32_16x16x32_bf16(af[m], bfr[n], acc[m][n], 0, 0, 0);

        asm volatile("" ::: "memory");
        __builtin_amdgcn_s_barrier();
    }

#pragma unroll
    for (int n = 0; n < 4; ++n) {
        const int gn = n0 + wn * 64 + n * 16 + lr;
        const float bv = bvv[n];
#pragma unroll
        for (int m = 0; m < MP; ++m) {
            const int gmb = m0 + wm * (16 * MP) + m * 16 + lg * 4;
            if (MODE == 0) {
                const int sec = gn >> 9, c = gn & 511;
                const int h = c >> 6, d = c & 63;
                const int b = gmb >> 12, t = gmb & 4095;
                if (sec == 2) {
                    ushort tmp[4];
#pragma unroll
                    for (int r = 0; r < 4; ++r) tmp[r] = f2b(acc[m][n][r] + bv);
                    *(ushort4*)&VTp[(size_t)(b * 8 + h) * 262144 + (size_t)d * 4096 + t] =
                        *(const ushort4*)tmp;
                } else {
                    const size_t idx0 = ((size_t)(b * 8 + h) * 4096 + t) * 64 + d;
#pragma unroll
                    for (int r = 0; r < 4; ++r) {
                        const float v = acc[m][n][r] + bv;
                        // Q scale = 0.125 * log2(e), folded in f32 -> exp2 domain
                        if (sec == 0) Qp[idx0 + (size_t)r * 64] = f2b(v * 0.18033688f);
                        else          Kp[idx0 + (size_t)r * 64] = f2b(v);
                    }
                }
            } else {
#pragma unroll
                for (int r = 0; r < 4; ++r)
                    outF[(size_t)(gmb + r) * 512 + gn] = acc[m][n][r] + bv;
            }
        }
    }
}

// ---------------- attention stream: 8 waves, one 256-row q-tile, KV [kv_lo,kv_hi) -------
// KV tile = 64 rows; 256-row q-tile qt (0..15) covers kv units [0, 4*qt+4).
// All 8 waves consume ONE shared KV stream in lockstep; staging = 2 glds16/thread.
// NO max-tracking (log2e pre-folded into Q; exp2 direct); pure-sum partials.
// ALWAYS writes a bf16 partial O^T [64][256] + l f32 [256] to its slot.
__device__ __forceinline__ void attn_run(const ushort* __restrict__ Qb,
                                         const ushort* __restrict__ Kb,
                                         const ushort* __restrict__ Vb,
                                         ushort* sm, int qt, int kv_lo, int kv_hi,
                                         int lane, int w, int tid,
                                         ushort* __restrict__ pOb,
                                         float* __restrict__ pL) {
    const int lg2 = lane >> 5, l31 = lane & 31, l7 = lane & 7;
    const int q0 = qt * 256;
    const int qbase = q0 + w * 32;

    // Q fragments: B-operand of 32x32x16 (col = lane&31 -> q row, k = (lane>>5)*8+e)
    bf16x8 qf[4];
#pragma unroll
    for (int ks = 0; ks < 4; ++ks)
        qf[ks] = *(const bf16x8*)&Qb[(size_t)(qbase + l31) * 64 + ks * 16 + lg2 * 8];
    asm volatile("s_waitcnt vmcnt(0)" ::: "memory");   // exact in-loop vmcnt counting
    __builtin_amdgcn_sched_barrier(0);

    const int srow = tid >> 3;                    // 0..63 (row within unit)
    const int sslot = (tid & 7) ^ (srow & 7);     // pre-swizzled global slot (rule 21)

    auto STAGE = [&](int buf, int kv0) {          // 2 glds16 per thread (512 thr = 16KB)
        glds16(Kb + (size_t)(kv0 + srow) * 64 + sslot * 8,
               (char*)sm + buf * 16384 + w * 1024);
        glds16(Vb + (size_t)srow * 4096 + kv0 + sslot * 8,
               (char*)sm + buf * 16384 + 8192 + w * 1024);
    };

    f32x16 oacc0 = z16(), oacc1 = z16();          // O^T: col=q (lane&31), rows=d pattern
    float lrun = 0.f;

    STAGE(0, kv_lo * 64);
    for (int it = kv_lo; it < kv_hi; ++it) {
        const int kv0 = it * 64;
        const int bsel = (it - kv_lo) & 1;
        if (it + 1 < kv_hi) {
            STAGE(bsel ^ 1, kv0 + 64);
            asm volatile("s_waitcnt vmcnt(2)" ::: "memory");
        } else {
            asm volatile("s_waitcnt vmcnt(0)" ::: "memory");
        }
        __builtin_amdgcn_sched_barrier(0);
        __builtin_amdgcn_s_barrier();             // all waves: buf[bsel] resident
        asm volatile("" ::: "memory");

        const bool live0 = (kv0 <= qbase + 31);
        const bool live1 = (kv0 + 32 <= qbase + 31);
        if (live0) {
            const ushort* bK = sm + bsel * 8192;
            const ushort* bV = bK + 4096;

            // S^T = K x Q^T : col = q = lane&31, kv rows reg-distributed
            f32x16 st0 = z16(), st1 = z16();
            __builtin_amdgcn_s_setprio(1);
#pragma unroll
            for (int ks = 0; ks < 4; ++ks) {
                bf16x8 kf = *(const bf16x8*)&bK[l31 * 64 + (((2 * ks + lg2) ^ l7)) * 8];
                st0 = __builtin_amdgcn_mfma_f32_32x32x16_bf16(kf, qf[ks], st0, 0, 0, 0);
            }
            if (live1) {
#pragma unroll
                for (int ks = 0; ks < 4; ++ks) {
                    bf16x8 kf = *(const bf16x8*)&bK[(32 + l31) * 64 + (((2 * ks + lg2) ^ l7)) * 8];
                    st1 = __builtin_amdgcn_mfma_f32_32x32x16_bf16(kf, qf[ks], st1, 0, 0, 0);
                }
            }
            __builtin_amdgcn_s_setprio(0);
            if (kv0 == qbase) {                   // diagonal tile 0
#pragma unroll
                for (int r = 0; r < 16; ++r) {
                    const int rowk = (r & 3) + 8 * (r >> 2) + 4 * lg2;
                    if (rowk > l31) st0[r] = -1e30f;
                }
            }
            if (live1 && kv0 + 32 == qbase) {     // diagonal tile 1
#pragma unroll
                for (int r = 0; r < 16; ++r) {
                    const int rowk = (r & 3) + 8 * (r >> 2) + 4 * lg2;
                    if (rowk > l31) st1[r] = -1e30f;
                }
            }

            // p = exp2(s) (log2e folded into Q); l accumulates per-lane
            float s0 = 0.f, s1 = 0.f, s2 = 0.f, s3 = 0.f;
#pragma unroll
            for (int r = 0; r < 16; r += 4) {
                st0[r]     = __builtin_amdgcn_exp2f(st0[r]);     s0 += st0[r];
                st0[r + 1] = __builtin_amdgcn_exp2f(st0[r + 1]); s1 += st0[r + 1];
                st0[r + 2] = __builtin_amdgcn_exp2f(st0[r + 2]); s2 += st0[r + 2];
                st0[r + 3] = __builtin_amdgcn_exp2f(st0[r + 3]); s3 += st0[r + 3];
            }
            if (live1) {
#pragma unroll
                for (int r = 0; r < 16; r += 4) {
                    st1[r]     = __builtin_amdgcn_exp2f(st1[r]);     s0 += st1[r];
                    st1[r + 1] = __builtin_amdgcn_exp2f(st1[r + 1]); s1 += st1[r + 1];
                    st1[r + 2] = __builtin_amdgcn_exp2f(st1[r + 2]); s2 += st1[r + 2];
                    st1[r + 3] = __builtin_amdgcn_exp2f(st1[r + 3]); s3 += st1[r + 3];
                }
            }
            lrun += (s0 + s1) + (s2 + s3);

            // P -> bf16 B-frag via cvt_pk + permlane32_swap (T12), then PV
#pragma unroll
            for (int stp = 0; stp < 4; ++stp) {
                if (stp >= 2 && !live1) continue;
                const int h = stp & 1;
                uint32_t a0, a1, b0, b1;
                if (stp < 2) {
                    a0 = cvt_pk_bf16(st0[h * 8 + 0], st0[h * 8 + 1]);
                    a1 = cvt_pk_bf16(st0[h * 8 + 2], st0[h * 8 + 3]);
                    b0 = cvt_pk_bf16(st0[h * 8 + 4], st0[h * 8 + 5]);
                    b1 = cvt_pk_bf16(st0[h * 8 + 6], st0[h * 8 + 7]);
                } else {
                    a0 = cvt_pk_bf16(st1[h * 8 + 0], st1[h * 8 + 1]);
                    a1 = cvt_pk_bf16(st1[h * 8 + 2], st1[h * 8 + 3]);
                    b0 = cvt_pk_bf16(st1[h * 8 + 4], st1[h * 8 + 5]);
                    b1 = cvt_pk_bf16(st1[h * 8 + 6], st1[h * 8 + 7]);
                }
                plane_swap(a0, b0);
                plane_swap(a1, b1);
                union { uint32_t u[4]; bf16x8 v; } pk;
                pk.u[0] = a0; pk.u[1] = a1; pk.u[2] = b0; pk.u[3] = b1;
                const int vs = (((2 * stp + lg2) ^ l7)) * 8;
                bf16x8 vf0 = *(const bf16x8*)&bV[l31 * 64 + vs];
                bf16x8 vf1 = *(const bf16x8*)&bV[(32 + l31) * 64 + vs];
                __builtin_amdgcn_s_setprio(1);
                oacc0 = __builtin_amdgcn_mfma_f32_32x32x16_bf16(vf0, pk.v, oacc0, 0, 0, 0);
                oacc1 = __builtin_amdgcn_mfma_f32_32x32x16_bf16(vf1, pk.v, oacc1, 0, 0, 0);
                __builtin_amdgcn_s_setprio(0);
            }
        }
        asm volatile("" ::: "memory");
        __builtin_amdgcn_s_barrier();             // all reads of buf[bsel] done
    }

    // deferred cross-half l reduction, then bf16 partial write
    lrun += __shfl_xor(lrun, 32);
    const int qc = w * 32 + l31;
#pragma unroll
    for (int r = 0; r < 16; ++r) {
        const int dd = (r & 3) + 8 * (r >> 2) + 4 * lg2;
        pOb[dd * 256 + qc]        = f2b(oacc0[r]);
        pOb[(dd + 32) * 256 + qc] = f2b(oacc1[r]);
    }
    if (lg2 == 0) pL[qc] = lrun;
}

// 4-way fold+split causal attention over 256-row q-tiles.
// Pair (p, 15-p), p in [0,8): heavy nH = 64-4p units, light nL = 4p+4, total 68.
// 4 streams of 17 units each: s -> p=s>>2, half=(s>>1)&1, sub=s&1.
// 512 blocks x 8 waves = 2 blocks/CU, all blocks exactly 17 units.
__global__ __launch_bounds__(512) void k_attn(const ushort* __restrict__ Q,
                                              const ushort* __restrict__ K,
                                              const ushort* __restrict__ VT,
                                              ushort* __restrict__ hOb,
                                              ushort* __restrict__ lOb,
                                              float* __restrict__ pL) {
    __shared__ __align__(16) ushort sm[16384];    // 32KB: 2 staging bufs x 16KB
    const int tid = threadIdx.x;
    const int lane = tid & 63, w = tid >> 6;      // w in [0,8)
    const int bh = blockIdx.x;
    const int s = blockIdx.y;                     // 0..31
    const int p = s >> 2, half = (s >> 1) & 1, sub = s & 1;
    const size_t base = (size_t)bh * 4096 * 64;
    const ushort* Qb = Q + base;
    const ushort* Kb = K + base;
    const ushort* Vb = VT + base;                 // [64][4096]

    const int pairbase = bh * 8 + p;
    if (half == 0) {
        const size_t hs = (size_t)(pairbase * 4 + sub);
        attn_run(Qb, Kb, Vb, sm, 15 - p, 17 * sub, 17 * sub + 17, lane, w, tid,
                 hOb + hs * 16384, pL + hs * 256);
    } else {
        const int nH2 = 30 - 4 * p;
        if (17 * sub < nH2) {
            const int hi = 17 * sub + 17 < nH2 ? 17 * sub + 17 : nH2;
            const size_t hs = (size_t)(pairbase * 4 + 2 + sub);
            attn_run(Qb, Kb, Vb, sm, 15 - p, 34 + 17 * sub, 34 + hi, lane, w, tid,
                     hOb + hs * 16384, pL + hs * 256);
        }
        if (17 * sub + 17 > nH2) {
            const int nL = 4 * p + 4;
            int llo = 17 * sub - nH2; if (llo < 0) llo = 0;
            int lhi = 17 * sub + 17 - nH2; if (lhi > nL) lhi = nL;
            const int lidx = (p <= 3) ? 0 : sub;
            const size_t ls = (size_t)(pairbase * 2 + lidx);
            attn_run(Qb, Kb, Vb, sm, p, llo, lhi, lane, w, tid,
                     lOb + ls * 16384, pL + (size_t)(512 + ls) * 256);
        }
    }
}

// merge the k bf16 partials of each (bh, qt), divide by summed l, write bf16 xb
__global__ __launch_bounds__(512) void k_merge(const ushort* __restrict__ hOb,
                                               const ushort* __restrict__ lOb,
                                               const float* __restrict__ pL,
                                               ushort* __restrict__ Outp) {
    const int bh = blockIdx.x;                    // 16
    const int qt = blockIdx.y;                    // 16
    const int tid = threadIdx.x;                  // 512
    const int q = tid >> 1, dh = (tid & 1) * 32;

    int k;
    const ushort* Ob;
    const float* Lb;
    if (qt >= 8) {                                // heavy tile: p = 15-qt
        const int p = 15 - qt;
        k = (p <= 3) ? 4 : 3;
        const size_t s0 = (size_t)((bh * 8 + p) * 4);
        Ob = hOb + s0 * 16384;
        Lb = pL + s0 * 256;
    } else {                                      // light tile: p = qt
        const int p = qt;
        k = (p <= 3) ? 1 : 2;
        const size_t s0 = (size_t)((bh * 8 + p) * 2);
        Ob = lOb + s0 * 16384;
        Lb = pL + (size_t)(512 + s0) * 256;
    }

    float osum[32];
#pragma unroll
    for (int e = 0; e < 32; ++e) osum[e] = 0.f;
    float lsum = 0.f;
    for (int j = 0; j < k; ++j) {
        const ushort* O = Ob + (size_t)j * 16384;
#pragma unroll
        for (int e = 0; e < 32; ++e) osum[e] += b2f(O[(dh + e) * 256 + q]);
        lsum += Lb[(size_t)j * 256 + q];
    }
    const float inv = 1.0f / lsum;
    ushort outv[32];
#pragma unroll
    for (int e = 0; e < 32; ++e) outv[e] = f2b(osum[e] * inv);
    const int b = bh >> 3, h = bh & 7;
    const int t = qt * 256 + q;
    ushort* op = Outp + ((size_t)(b * 4096 + t) * 512 + h * 64 + dh);
#pragma unroll
    for (int j = 0; j < 4; ++j) *(uint4*)&op[j * 8] = *(const uint4*)&outv[j * 8];
}

extern "C" void kernel_launch(void* const* d_in, const int* in_sizes, int n_in,
                              void* d_out, int out_size, void* d_ws, size_t ws_size,
                              hipStream_t stream) {
    const float* x    = (const float*)d_in[0];
    const float* Wqkv = (const float*)d_in[1];
    const float* bqkv = (const float*)d_in[2];
    const float* Wout = (const float*)d_in[3];
    const float* bout = (const float*)d_in[4];
    float* out = (float*)d_out;

    char* ws = (char*)d_ws;
    ushort* xb    = (ushort*)(ws);                 // 8 MB (attn out)
    ushort* wqkvT = (ushort*)(ws + 8388608);       // 1.5 MB (dead after gemm<0>; pL reuses)
    ushort* woutT = (ushort*)(ws + 9961472);       // 0.5 MB
    ushort* Qp    = (ushort*)(ws + 10485760);      // 8 MB
    ushort* Kp    = (ushort*)(ws + 18874368);      // 8 MB
    ushort* VTp   = (ushort*)(ws + 27262976);      // 8 MB
    ushort* hOb   = (ushort*)(ws + 35651584);      // 16 MB: 512 heavy bf16 slots x 32KB
    ushort* lOb   = (ushort*)d_out;                // 8 MB: 256 light bf16 slots (scratch;
                                                   // gemm<1> overwrites d_out afterwards)
    float*  pL    = (float*)(ws + 8388608);        // 768 KB in dead wqkvT region

    k_prep<<<3072, 256, 0, stream>>>(x, xb, Wqkv, wqkvT, Wout, woutT);
    k_gemm<0, 4><<<dim3(64, 12), 256, 0, stream>>>(xb, wqkvT, bqkv, nullptr, Qp, Kp, VTp, 512);
    k_attn<<<dim3(16, 32), 512, 0, stream>>>(Qp, Kp, VTp, hOb, lOb, pL);
    k_merge<<<dim3(16, 16), 512, 0, stream>>>(hOb, lOb, pL, xb);
    k_gemm<1, 2><<<dim3(128, 4), 256, 0, stream>>>(xb, woutT, bout, out, nullptr, nullptr, nullptr, 512);
}

// Round 20
// 96.648 us; speedup vs baseline: 1.0068x; 1.0051x over previous
//
#include <hip/hip_runtime.h>
#include <hip/hip_bf16.h>
#include <cstdint>
#include <cstddef>

typedef __attribute__((ext_vector_type(8))) __bf16 bf16x8;
typedef __attribute__((ext_vector_type(4))) float f32x4;
typedef __attribute__((ext_vector_type(16))) float f32x16;

__device__ __forceinline__ ushort f2b(float x) {
    union { float f; uint32_t u; } v; v.f = x;
    uint32_t r = v.u + 0x7FFFu + ((v.u >> 16) & 1u);   // RNE
    return (ushort)(r >> 16);
}

__device__ __forceinline__ float b2f(ushort u) {
    union { uint32_t u; float f; } v; v.u = (uint32_t)u << 16;
    return v.f;
}

__device__ __forceinline__ void glds16(const void* g, void* l) {
    __builtin_amdgcn_global_load_lds(
        (const __attribute__((address_space(1))) void*)g,
        (__attribute__((address_space(3))) void*)l, 16, 0, 0);
}

__device__ __forceinline__ uint32_t cvt_pk_bf16(float lo, float hi) {
    uint32_t r;
    asm("v_cvt_pk_bf16_f32 %0, %1, %2" : "=v"(r) : "v"(lo), "v"(hi));
    return r;
}

// v_permlane32_swap_b32 a, b:  a.hi32lanes <-> b.lo32lanes
__device__ __forceinline__ void plane_swap(uint32_t& a, uint32_t& b) {
    asm volatile("v_permlane32_swap_b32 %0, %1" : "+v"(a), "+v"(b));
}

__device__ __forceinline__ f32x16 z16() {
    f32x16 v;
#pragma unroll
    for (int i = 0; i < 16; ++i) v[i] = 0.f;
    return v;
}

// ---------------- fused prep: x->bf16 convert + both weight transposes ----------------
__global__ __launch_bounds__(256) void k_prep(const float* __restrict__ x,
                                              ushort* __restrict__ xb,
                                              const float* __restrict__ Wqkv,
                                              ushort* __restrict__ wqkvT,
                                              const float* __restrict__ Wout,
                                              ushort* __restrict__ woutT) {
    __shared__ float tile[32][33];
    const int id = blockIdx.x;
    const int tid = threadIdx.x;
    if (id < 2048) {
        const int i = id * 256 + tid;
        const float4* p = (const float4*)x + (size_t)i * 2;
        float4 a = p[0], b = p[1];
        ushort o[8] = { f2b(a.x), f2b(a.y), f2b(a.z), f2b(a.w),
                        f2b(b.x), f2b(b.y), f2b(b.z), f2b(b.w) };
        *(uint4*)(xb + (size_t)i * 8) = *(const uint4*)o;
        return;
    }
    const float* in;
    ushort* out;
    int R = 512, C, c0, r0;
    if (id < 2816) {
        in = Wqkv; out = wqkvT; C = 1536;
        c0 = ((id - 2048) % 48) * 32; r0 = ((id - 2048) / 48) * 32;
    } else {
        in = Wout; out = woutT; C = 512;
        c0 = ((id - 2816) % 16) * 32; r0 = ((id - 2816) / 16) * 32;
    }
    const int tx = tid & 31, ty = tid >> 5;       // (32,8)
#pragma unroll
    for (int i = 0; i < 32; i += 8)
        tile[ty + i][tx] = in[(size_t)(r0 + ty + i) * C + c0 + tx];
    __syncthreads();
#pragma unroll
    for (int i = 0; i < 32; i += 8)
        out[(size_t)(c0 + ty + i) * R + r0 + tx] = f2b(tile[tx][ty + i]);
}

// ---------------- bf16 GEMM, A [M][K] x BT [N][K] (=B^T), (32*MP)x128 tile -------------
template <int MODE, int MP>
__global__ __launch_bounds__(256) void k_gemm(const ushort* __restrict__ A,
                                              const ushort* __restrict__ BT,
                                              const float* __restrict__ bias,
                                              float* __restrict__ outF,
                                              ushort* __restrict__ Qp,
                                              ushort* __restrict__ Kp,
                                              ushort* __restrict__ VTp,
                                              int K) {
    __shared__ __align__(16) ushort lA[2][MP * 1024];
    __shared__ __align__(16) ushort lB[2][4096];
    const int tid = threadIdx.x;
    const int lane = tid & 63, lr = lane & 15, lg = lane >> 4;
    const int wid = tid >> 6, wm = wid >> 1, wn = wid & 1;
    const int m0 = blockIdx.x * (32 * MP), n0 = blockIdx.y * 128;

    const ushort* ga = A + (size_t)(m0 + (tid >> 2)) * K + (tid & 3) * 8;
    const ushort* gb = BT + (size_t)(n0 + (tid >> 2)) * K + (tid & 3) * 8;
    const size_t rstep = (size_t)64 * K;

    float bvv[4];
#pragma unroll
    for (int n = 0; n < 4; ++n) bvv[n] = bias[n0 + wn * 64 + n * 16 + lr];
    asm volatile("s_waitcnt vmcnt(0)" ::: "memory");
    __builtin_amdgcn_sched_barrier(0);

    f32x4 zero = {0.f, 0.f, 0.f, 0.f};
    f32x4 acc[MP][4];
#pragma unroll
    for (int i = 0; i < MP; ++i)
#pragma unroll
        for (int j = 0; j < 4; ++j) acc[i][j] = zero;

    auto STG = [&](int buf, int k0) {
        glds16(ga + k0, &lA[buf][tid * 8]);
        if constexpr (MP == 4) glds16(ga + k0 + rstep, &lA[buf][2048 + tid * 8]);
        glds16(gb + k0,         &lB[buf][tid * 8]);
        glds16(gb + k0 + rstep, &lB[buf][2048 + tid * 8]);
    };

    const int NT = K >> 5;
    STG(0, 0);
    for (int it = 0; it < NT; ++it) {
        const int bsel = it & 1;
        if (it + 1 < NT) {
            STG(bsel ^ 1, (it + 1) * 32);
            if constexpr (MP == 4) {
                asm volatile("s_waitcnt vmcnt(4)" ::: "memory");
            } else {
                asm volatile("s_waitcnt vmcnt(3)" ::: "memory");
            }
        } else {
            asm volatile("s_waitcnt vmcnt(0)" ::: "memory");
        }
        __builtin_amdgcn_sched_barrier(0);
        __builtin_amdgcn_s_barrier();
        asm volatile("" ::: "memory");

        bf16x8 af[MP], bfr[4];
#pragma unroll
        for (int m = 0; m < MP; ++m)
            af[m] = *(const bf16x8*)&lA[bsel][(wm * (16 * MP) + m * 16 + lr) * 32 + lg * 8];
#pragma unroll
        for (int n = 0; n < 4; ++n)
            bfr[n] = *(const bf16x8*)&lB[bsel][(wn * 64 + n * 16 + lr) * 32 + lg * 8];
#pragma unroll
        for (int m = 0; m < MP; ++m)
#pragma unroll
            for (int n = 0; n < 4; ++n)
                acc[m][n] = __builtin_amdgcn_mfma_f32_16x16x32_bf16(af[m], bfr[n], acc[m][n], 0, 0, 0);

        asm volatile("" ::: "memory");
        __builtin_amdgcn_s_barrier();
    }

#pragma unroll
    for (int n = 0; n < 4; ++n) {
        const int gn = n0 + wn * 64 + n * 16 + lr;
        const float bv = bvv[n];
#pragma unroll
        for (int m = 0; m < MP; ++m) {
            const int gmb = m0 + wm * (16 * MP) + m * 16 + lg * 4;
            if (MODE == 0) {
                const int sec = gn >> 9, c = gn & 511;
                const int h = c >> 6, d = c & 63;
                const int b = gmb >> 12, t = gmb & 4095;
                if (sec == 2) {
                    ushort tmp[4];
#pragma unroll
                    for (int r = 0; r < 4; ++r) tmp[r] = f2b(acc[m][n][r] + bv);
                    *(ushort4*)&VTp[(size_t)(b * 8 + h) * 262144 + (size_t)d * 4096 + t] =
                        *(const ushort4*)tmp;
                } else {
                    const size_t idx0 = ((size_t)(b * 8 + h) * 4096 + t) * 64 + d;
#pragma unroll
                    for (int r = 0; r < 4; ++r) {
                        const float v = acc[m][n][r] + bv;
                        // Q scale = 0.125 * log2(e), folded in f32 -> exp2 domain
                        if (sec == 0) Qp[idx0 + (size_t)r * 64] = f2b(v * 0.18033688f);
                        else          Kp[idx0 + (size_t)r * 64] = f2b(v);
                    }
                }
            } else {
#pragma unroll
                for (int r = 0; r < 4; ++r)
                    outF[(size_t)(gmb + r) * 512 + gn] = acc[m][n][r] + bv;
            }
        }
    }
}

// ---------------- attention stream: 8 waves, one 256-row q-tile, KV [kv_lo,kv_hi) -------
// (R17/R19 verbatim — best verified: 46.8 us.)
// KV tile = 64 rows; 256-row q-tile qt (0..15) covers kv units [0, 4*qt+4).
// All 8 waves consume ONE shared KV stream in lockstep; staging = 2 glds16/thread.
// NO max-tracking (log2e pre-folded into Q; exp2 direct); pure-sum partials.
// ALWAYS writes a bf16 partial O^T [64][256] + l f32 [256] to its slot.
__device__ __forceinline__ void attn_run(const ushort* __restrict__ Qb,
                                         const ushort* __restrict__ Kb,
                                         const ushort* __restrict__ Vb,
                                         ushort* sm, int qt, int kv_lo, int kv_hi,
                                         int lane, int w, int tid,
                                         ushort* __restrict__ pOb,
                                         float* __restrict__ pL) {
    const int lg2 = lane >> 5, l31 = lane & 31, l7 = lane & 7;
    const int q0 = qt * 256;
    const int qbase = q0 + w * 32;

    // Q fragments: B-operand of 32x32x16 (col = lane&31 -> q row, k = (lane>>5)*8+e)
    bf16x8 qf[4];
#pragma unroll
    for (int ks = 0; ks < 4; ++ks)
        qf[ks] = *(const bf16x8*)&Qb[(size_t)(qbase + l31) * 64 + ks * 16 + lg2 * 8];
    asm volatile("s_waitcnt vmcnt(0)" ::: "memory");   // exact in-loop vmcnt counting
    __builtin_amdgcn_sched_barrier(0);

    const int srow = tid >> 3;                    // 0..63 (row within unit)
    const int sslot = (tid & 7) ^ (srow & 7);     // pre-swizzled global slot (rule 21)

    auto STAGE = [&](int buf, int kv0) {          // 2 glds16 per thread (512 thr = 16KB)
        glds16(Kb + (size_t)(kv0 + srow) * 64 + sslot * 8,
               (char*)sm + buf * 16384 + w * 1024);
        glds16(Vb + (size_t)srow * 4096 + kv0 + sslot * 8,
               (char*)sm + buf * 16384 + 8192 + w * 1024);
    };

    f32x16 oacc0 = z16(), oacc1 = z16();          // O^T: col=q (lane&31), rows=d pattern
    float lrun = 0.f;

    STAGE(0, kv_lo * 64);
    for (int it = kv_lo; it < kv_hi; ++it) {
        const int kv0 = it * 64;
        const int bsel = (it - kv_lo) & 1;
        if (it + 1 < kv_hi) {
            STAGE(bsel ^ 1, kv0 + 64);
            asm volatile("s_waitcnt vmcnt(2)" ::: "memory");
        } else {
            asm volatile("s_waitcnt vmcnt(0)" ::: "memory");
        }
        __builtin_amdgcn_sched_barrier(0);
        __builtin_amdgcn_s_barrier();             // all waves: buf[bsel] resident
        asm volatile("" ::: "memory");

        const bool live0 = (kv0 <= qbase + 31);
        const bool live1 = (kv0 + 32 <= qbase + 31);
        if (live0) {
            const ushort* bK = sm + bsel * 8192;
            const ushort* bV = bK + 4096;

            // S^T = K x Q^T : col = q = lane&31, kv rows reg-distributed
            f32x16 st0 = z16(), st1 = z16();
            __builtin_amdgcn_s_setprio(1);
#pragma unroll
            for (int ks = 0; ks < 4; ++ks) {
                bf16x8 kf = *(const bf16x8*)&bK[l31 * 64 + (((2 * ks + lg2) ^ l7)) * 8];
                st0 = __builtin_amdgcn_mfma_f32_32x32x16_bf16(kf, qf[ks], st0, 0, 0, 0);
            }
            if (live1) {
#pragma unroll
                for (int ks = 0; ks < 4; ++ks) {
                    bf16x8 kf = *(const bf16x8*)&bK[(32 + l31) * 64 + (((2 * ks + lg2) ^ l7)) * 8];
                    st1 = __builtin_amdgcn_mfma_f32_32x32x16_bf16(kf, qf[ks], st1, 0, 0, 0);
                }
            }
            __builtin_amdgcn_s_setprio(0);
            if (kv0 == qbase) {                   // diagonal tile 0
#pragma unroll
                for (int r = 0; r < 16; ++r) {
                    const int rowk = (r & 3) + 8 * (r >> 2) + 4 * lg2;
                    if (rowk > l31) st0[r] = -1e30f;
                }
            }
            if (live1 && kv0 + 32 == qbase) {     // diagonal tile 1
#pragma unroll
                for (int r = 0; r < 16; ++r) {
                    const int rowk = (r & 3) + 8 * (r >> 2) + 4 * lg2;
                    if (rowk > l31) st1[r] = -1e30f;
                }
            }

            // p = exp2(s) (log2e folded into Q); l accumulates per-lane
            float s0 = 0.f, s1 = 0.f, s2 = 0.f, s3 = 0.f;
#pragma unroll
            for (int r = 0; r < 16; r += 4) {
                st0[r]     = __builtin_amdgcn_exp2f(st0[r]);     s0 += st0[r];
                st0[r + 1] = __builtin_amdgcn_exp2f(st0[r + 1]); s1 += st0[r + 1];
                st0[r + 2] = __builtin_amdgcn_exp2f(st0[r + 2]); s2 += st0[r + 2];
                st0[r + 3] = __builtin_amdgcn_exp2f(st0[r + 3]); s3 += st0[r + 3];
            }
            if (live1) {
#pragma unroll
                for (int r = 0; r < 16; r += 4) {
                    st1[r]     = __builtin_amdgcn_exp2f(st1[r]);     s0 += st1[r];
                    st1[r + 1] = __builtin_amdgcn_exp2f(st1[r + 1]); s1 += st1[r + 1];
                    st1[r + 2] = __builtin_amdgcn_exp2f(st1[r + 2]); s2 += st1[r + 2];
                    st1[r + 3] = __builtin_amdgcn_exp2f(st1[r + 3]); s3 += st1[r + 3];
                }
            }
            lrun += (s0 + s1) + (s2 + s3);

            // P -> bf16 B-frag via cvt_pk + permlane32_swap (T12), then PV
#pragma unroll
            for (int stp = 0; stp < 4; ++stp) {
                if (stp >= 2 && !live1) continue;
                const int h = stp & 1;
                uint32_t a0, a1, b0, b1;
                if (stp < 2) {
                    a0 = cvt_pk_bf16(st0[h * 8 + 0], st0[h * 8 + 1]);
                    a1 = cvt_pk_bf16(st0[h * 8 + 2], st0[h * 8 + 3]);
                    b0 = cvt_pk_bf16(st0[h * 8 + 4], st0[h * 8 + 5]);
                    b1 = cvt_pk_bf16(st0[h * 8 + 6], st0[h * 8 + 7]);
                } else {
                    a0 = cvt_pk_bf16(st1[h * 8 + 0], st1[h * 8 + 1]);
                    a1 = cvt_pk_bf16(st1[h * 8 + 2], st1[h * 8 + 3]);
                    b0 = cvt_pk_bf16(st1[h * 8 + 4], st1[h * 8 + 5]);
                    b1 = cvt_pk_bf16(st1[h * 8 + 6], st1[h * 8 + 7]);
                }
                plane_swap(a0, b0);
                plane_swap(a1, b1);
                union { uint32_t u[4]; bf16x8 v; } pk;
                pk.u[0] = a0; pk.u[1] = a1; pk.u[2] = b0; pk.u[3] = b1;
                const int vs = (((2 * stp + lg2) ^ l7)) * 8;
                bf16x8 vf0 = *(const bf16x8*)&bV[l31 * 64 + vs];
                bf16x8 vf1 = *(const bf16x8*)&bV[(32 + l31) * 64 + vs];
                __builtin_amdgcn_s_setprio(1);
                oacc0 = __builtin_amdgcn_mfma_f32_32x32x16_bf16(vf0, pk.v, oacc0, 0, 0, 0);
                oacc1 = __builtin_amdgcn_mfma_f32_32x32x16_bf16(vf1, pk.v, oacc1, 0, 0, 0);
                __builtin_amdgcn_s_setprio(0);
            }
        }
        asm volatile("" ::: "memory");
        __builtin_amdgcn_s_barrier();             // all reads of buf[bsel] done
    }

    // deferred cross-half l reduction, then bf16 partial write
    lrun += __shfl_xor(lrun, 32);
    const int qc = w * 32 + l31;
#pragma unroll
    for (int r = 0; r < 16; ++r) {
        const int dd = (r & 3) + 8 * (r >> 2) + 4 * lg2;
        pOb[dd * 256 + qc]        = f2b(oacc0[r]);
        pOb[(dd + 32) * 256 + qc] = f2b(oacc1[r]);
    }
    if (lg2 == 0) pL[qc] = lrun;
}

// 4-way fold+split causal attention over 256-row q-tiles.
// Pair (p, 15-p), p in [0,8): heavy nH = 64-4p units, light nL = 4p+4, total 68.
// 4 streams of 17 units each: s -> p=s>>2, half=(s>>1)&1, sub=s&1.
// 512 blocks x 8 waves = 2 blocks/CU, all blocks exactly 17 units.
__global__ __launch_bounds__(512) void k_attn(const ushort* __restrict__ Q,
                                              const ushort* __restrict__ K,
                                              const ushort* __restrict__ VT,
                                              ushort* __restrict__ hOb,
                                              ushort* __restrict__ lOb,
                                              float* __restrict__ pL) {
    __shared__ __align__(16) ushort sm[16384];    // 32KB: 2 staging bufs x 16KB
    const int tid = threadIdx.x;
    const int lane = tid & 63, w = tid >> 6;      // w in [0,8)
    const int bh = blockIdx.x;
    const int s = blockIdx.y;                     // 0..31
    const int p = s >> 2, half = (s >> 1) & 1, sub = s & 1;
    const size_t base = (size_t)bh * 4096 * 64;
    const ushort* Qb = Q + base;
    const ushort* Kb = K + base;
    const ushort* Vb = VT + base;                 // [64][4096]

    const int pairbase = bh * 8 + p;
    if (half == 0) {
        const size_t hs = (size_t)(pairbase * 4 + sub);
        attn_run(Qb, Kb, Vb, sm, 15 - p, 17 * sub, 17 * sub + 17, lane, w, tid,
                 hOb + hs * 16384, pL + hs * 256);
    } else {
        const int nH2 = 30 - 4 * p;
        if (17 * sub < nH2) {
            const int hi = 17 * sub + 17 < nH2 ? 17 * sub + 17 : nH2;
            const size_t hs = (size_t)(pairbase * 4 + 2 + sub);
            attn_run(Qb, Kb, Vb, sm, 15 - p, 34 + 17 * sub, 34 + hi, lane, w, tid,
                     hOb + hs * 16384, pL + hs * 256);
        }
        if (17 * sub + 17 > nH2) {
            const int nL = 4 * p + 4;
            int llo = 17 * sub - nH2; if (llo < 0) llo = 0;
            int lhi = 17 * sub + 17 - nH2; if (lhi > nL) lhi = nL;
            const int lidx = (p <= 3) ? 0 : sub;
            const size_t ls = (size_t)(pairbase * 2 + lidx);
            attn_run(Qb, Kb, Vb, sm, p, llo, lhi, lane, w, tid,
                     lOb + ls * 16384, pL + (size_t)(512 + ls) * 256);
        }
    }
}

// ---------------- vectorized 3-phase merge ----------------
// Phase 0: 256 thr compute 1/lsum[q] -> LDS.
// Phase 1: thread (dd=tid&63, qg=tid>>6) reads each slot's [dd][qg*32..+32) as
//          4x uint4 (64B contiguous), accumulates f32, scales, rounds once,
//          writes bf16 to LDS [256 q][72].
// Phase 2: thread (q=tid>>1, dh) copies its 64B row chunk LDS -> global.
__global__ __launch_bounds__(512) void k_merge(const ushort* __restrict__ hOb,
                                               const ushort* __restrict__ lOb,
                                               const float* __restrict__ pL,
                                               ushort* __restrict__ Outp) {
    __shared__ float Ls[256];
    __shared__ __align__(16) ushort eps[256 * 72];
    const int bh = blockIdx.x;                    // 16
    const int qt = blockIdx.y;                    // 16
    const int tid = threadIdx.x;                  // 512

    int k;
    const ushort* Ob;
    const float* Lb;
    if (qt >= 8) {                                // heavy tile: p = 15-qt
        const int p = 15 - qt;
        k = (p <= 3) ? 4 : 3;
        const size_t s0 = (size_t)((bh * 8 + p) * 4);
        Ob = hOb + s0 * 16384;
        Lb = pL + s0 * 256;
    } else {                                      // light tile: p = qt
        const int p = qt;
        k = (p <= 3) ? 1 : 2;
        const size_t s0 = (size_t)((bh * 8 + p) * 2);
        Ob = lOb + s0 * 16384;
        Lb = pL + (size_t)(512 + s0) * 256;
    }

    // phase 0: reciprocal of summed l
    if (tid < 256) {
        float lsum = 0.f;
        for (int j = 0; j < k; ++j) lsum += Lb[(size_t)j * 256 + tid];
        Ls[tid] = 1.0f / lsum;
    }
    __syncthreads();

    // phase 1: vectorized accumulate over slots (dd-major layout)
    {
        const int dd = tid & 63, qg = tid >> 6;   // qg in [0,8)
        const int qq = qg * 32;
        float osum[32];
#pragma unroll
        for (int e = 0; e < 32; ++e) osum[e] = 0.f;
        for (int j = 0; j < k; ++j) {
            const ushort* O = Ob + (size_t)j * 16384 + dd * 256 + qq;
#pragma unroll
            for (int v = 0; v < 4; ++v) {
                uint4 pkv = *(const uint4*)&O[v * 8];
                const ushort* us = (const ushort*)&pkv;
#pragma unroll
                for (int e2 = 0; e2 < 8; ++e2) osum[v * 8 + e2] += b2f(us[e2]);
            }
        }
#pragma unroll
        for (int e = 0; e < 32; ++e)
            eps[(qq + e) * 72 + dd] = f2b(osum[e] * Ls[qq + e]);
    }
    __syncthreads();

    // phase 2: coalesced output
    const int q = tid >> 1, dh = (tid & 1) * 32;
    const int b = bh >> 3, h = bh & 7;
    const int t = qt * 256 + q;
    ushort* op = Outp + ((size_t)(b * 4096 + t) * 512 + h * 64 + dh);
    const ushort* er = &eps[q * 72 + dh];
#pragma unroll
    for (int j = 0; j < 4; ++j) *(uint4*)&op[j * 8] = *(const uint4*)&er[j * 8];
}

extern "C" void kernel_launch(void* const* d_in, const int* in_sizes, int n_in,
                              void* d_out, int out_size, void* d_ws, size_t ws_size,
                              hipStream_t stream) {
    const float* x    = (const float*)d_in[0];
    const float* Wqkv = (const float*)d_in[1];
    const float* bqkv = (const float*)d_in[2];
    const float* Wout = (const float*)d_in[3];
    const float* bout = (const float*)d_in[4];
    float* out = (float*)d_out;

    char* ws = (char*)d_ws;
    ushort* xb    = (ushort*)(ws);                 // 8 MB (attn out)
    ushort* wqkvT = (ushort*)(ws + 8388608);       // 1.5 MB (dead after gemm<0>; pL reuses)
    ushort* woutT = (ushort*)(ws + 9961472);       // 0.5 MB
    ushort* Qp    = (ushort*)(ws + 10485760);      // 8 MB
    ushort* Kp    = (ushort*)(ws + 18874368);      // 8 MB
    ushort* VTp   = (ushort*)(ws + 27262976);      // 8 MB
    ushort* hOb   = (ushort*)(ws + 35651584);      // 16 MB: 512 heavy bf16 slots x 32KB
    ushort* lOb   = (ushort*)d_out;                // 8 MB: 256 light bf16 slots (scratch;
                                                   // gemm<1> overwrites d_out afterwards)
    float*  pL    = (float*)(ws + 8388608);        // 768 KB in dead wqkvT region

    k_prep<<<3072, 256, 0, stream>>>(x, xb, Wqkv, wqkvT, Wout, woutT);
    k_gemm<0, 4><<<dim3(64, 12), 256, 0, stream>>>(xb, wqkvT, bqkv, nullptr, Qp, Kp, VTp, 512);
    k_attn<<<dim3(16, 32), 512, 0, stream>>>(Qp, Kp, VTp, hOb, lOb, pL);
    k_merge<<<dim3(16, 16), 512, 0, stream>>>(hOb, lOb, pL, xb);
    k_gemm<1, 2><<<dim3(128, 4), 256, 0, stream>>>(xb, woutT, bout, out, nullptr, nullptr, nullptr, 512);
}